// Round 1
// 413.278 us; speedup vs baseline: 1.1287x; 1.1287x over previous
//
#include <hip/hip_runtime.h>
#include <stdint.h>

// ---------------------------------------------------------------------------
// MultiHeadAttention: B=8 S=1024 QKV=1024 H=16 E=64 OUT=1024.
// fp32 in / fp32 out, bf16 MFMA internals, fp32 accum.
// R8: GEMM overhaul. The 4 projection/output GEMMs were reg-staged (fp32 cvt
// in the staging path) at ~220 TF. Replaced with m97-structure gemm_bb:
//   - q/k/v pre-converted fp32->bf16 once (cvt_wo, grid 2048) into d_out
//     used as a 16MB scratch (sequentially reused; final GEMM writes d_out
//     last, so no aliasing hazard, ws stays at 56 MB).
//   - gemm_bb<F32OUT>: 128x128 tile, BK=64, LINEAR LDS [128][64] bf16,
//     staged via __builtin_amdgcn_global_load_lds width=16 (wave-uniform
//     LDS base + lane*16; per-lane global src), 2 barriers/K-step.
//     Reference: m97/m103 874-912 TF at this exact structure.
// flash_attn is byte-identical to R7 (control for this round).
// ws: [Qp 16][Kp 16][Vp 16][WqT 2|WkT 2|WvT 2|WoB 2] = 56 MB.
// MFMA 16x16x32 bf16 maps (HW-verified m89/m91):
//   A[m=lane&15][k=quad*8+j], B[k=quad*8+j][n=lane&15], D[row=quad*4+r][col]
// ---------------------------------------------------------------------------

typedef __bf16 bf16x8 __attribute__((ext_vector_type(8)));
typedef float f32x4 __attribute__((ext_vector_type(4)));

typedef __attribute__((address_space(3))) uint32_t lds_u32;
typedef const __attribute__((address_space(1))) uint32_t glb_u32;

__device__ __forceinline__ ushort f2bf(float f) {
  uint32_t x = __float_as_uint(f);
  x += 0x7fff + ((x >> 16) & 1);  // RNE
  return (ushort)(x >> 16);
}
__device__ __forceinline__ bf16x8 ld8(const ushort* p) {
  union { uint4 u; bf16x8 b; } c;
  c.u = *reinterpret_cast<const uint4*>(p);
  return c.b;
}
// 16 contiguous fp32 -> 16 bf16 (two uint4 stores; works for LDS or global)
__device__ __forceinline__ void cvt16(const float* __restrict__ src,
                                      ushort* __restrict__ dst) {
  union { uint4 u[2]; ushort s[16]; } o;
#pragma unroll
  for (int i = 0; i < 4; ++i) {
    const float4 f = reinterpret_cast<const float4*>(src)[i];
    o.s[4 * i + 0] = f2bf(f.x);
    o.s[4 * i + 1] = f2bf(f.y);
    o.s[4 * i + 2] = f2bf(f.z);
    o.s[4 * i + 3] = f2bf(f.w);
  }
  reinterpret_cast<uint4*>(dst)[0] = o.u[0];
  reinterpret_cast<uint4*>(dst)[1] = o.u[1];
}

// global->LDS DMA, 16B per lane. LDS dest is wave-uniform base + lane*16
// (hardware semantics, m104/m108) -> pass the wave's base; global src is
// per-lane. Size must be a literal (16).
__device__ __forceinline__ void gld16(const ushort* g, ushort* l) {
  __builtin_amdgcn_global_load_lds((glb_u32*)g, (lds_u32*)l, 16, 0, 0);
}

// --------------------------------------------------------------------------
// W[16][1024][64] fp32 -> WT[1024][1024] bf16 (WT[n=h*64+e][k]).
// grid 256 = (h, ktile), block 256. Coverage: 256 thr x 16 = 64x64 tile. OK
// --------------------------------------------------------------------------
__global__ __launch_bounds__(256) void prep_wt(const float* __restrict__ W,
                                               ushort* __restrict__ WT) {
  __shared__ __align__(16) ushort tile[64 * 72];
  const int h = blockIdx.x >> 4;
  const int kt = blockIdx.x & 15;
  const int t = threadIdx.x;
  const int row = t >> 2;        // k within tile
  const int ch = (t & 3) * 16;   // e chunk
  cvt16(W + ((size_t)h * 1024 + kt * 64 + row) * 64 + ch, &tile[row * 72 + ch]);
  __syncthreads();
  const int e = t >> 2;
  const int kc = (t & 3) * 16;
  ushort vals[16];
#pragma unroll
  for (int j = 0; j < 16; ++j) vals[j] = tile[(kc + j) * 72 + e];
  ushort* dst = WT + (size_t)(h * 64 + e) * 1024 + kt * 64 + kc;
  reinterpret_cast<uint4*>(dst)[0] = *reinterpret_cast<uint4*>(&vals[0]);
  reinterpret_cast<uint4*>(dst)[1] = *reinterpret_cast<uint4*>(&vals[8]);
}

// fp32 -> bf16 elementwise, 16 elems/thread. grid = elems/4096.
__global__ __launch_bounds__(256) void cvt_wo(const float* __restrict__ src,
                                              ushort* __restrict__ dst) {
  const int i = (blockIdx.x * 256 + threadIdx.x) * 16;
  cvt16(src + i, dst + i);
}

// --------------------------------------------------------------------------
// C[8192][1024] = A[8192][1024] bf16 @ Bt[1024][1024] bf16 ^T (+ bias).
// m97 structure: 128x128 tile, BK=64, 256 thr (4 waves, 2x2 wave grid,
// 4x4 MFMA each). LINEAR LDS [128][64] (global_load_lds requires contiguous
// lane-order dest; the resulting ds_read bank conflicts are priced into the
// 874-912 TF reference, m98/m103). Staging: per wave 4 issues/operand,
// each 64 lanes x 16B = 1KB = 8 rows. grid dim3(8, 64).
// F32OUT=false: C bf16, no bias. F32OUT=true: C fp32 + bias.
// --------------------------------------------------------------------------
template <bool F32OUT>
__global__ __launch_bounds__(256) void gemm_bb(const ushort* __restrict__ A,
                                               const ushort* __restrict__ Bt,
                                               const float* __restrict__ bias,
                                               void* __restrict__ Cv) {
  __shared__ __align__(16) ushort As[128 * 64];
  __shared__ __align__(16) ushort Bs[128 * 64];
  const int n0 = blockIdx.x * 128;
  const int m0 = blockIdx.y * 128;
  const int t = threadIdx.x;
  const int lane = t & 63;
  const int w = t >> 6;
  const int wm = w >> 1, wn = w & 1;
  const int col = lane & 15;
  const int quad = lane >> 4;
  // staging geometry: row-within-wave-chunk + 8-ushort column chunk
  const int gr = lane >> 3;        // 0..7
  const int gc = (lane & 7) * 8;   // ushort col 0..56

  f32x4 acc[4][4];
#pragma unroll
  for (int i = 0; i < 4; ++i)
#pragma unroll
    for (int j = 0; j < 4; ++j) acc[i][j] = (f32x4){0.f, 0.f, 0.f, 0.f};

  // per-lane global sources; wave-uniform LDS bases (lane index folds in HW)
  const ushort* a_src = A + (size_t)(m0 + w * 8 + gr) * 1024 + gc;
  const ushort* b_src = Bt + (size_t)(n0 + w * 8 + gr) * 1024 + gc;
  ushort* as_base = &As[(w * 8) * 64];
  ushort* bs_base = &Bs[(w * 8) * 64];

  for (int k0 = 0; k0 < 1024; k0 += 64) {
#pragma unroll
    for (int c = 0; c < 4; ++c) {
      gld16(a_src + (size_t)c * 32 * 1024 + k0, as_base + c * 32 * 64);
      gld16(b_src + (size_t)c * 32 * 1024 + k0, bs_base + c * 32 * 64);
    }
    __syncthreads();  // drains vmcnt(0) before barrier (compiler-inserted)

#pragma unroll
    for (int half = 0; half < 2; ++half) {
      bf16x8 af[4], bf[4];
#pragma unroll
      for (int i = 0; i < 4; ++i)
        af[i] = ld8(&As[(wm * 64 + i * 16 + col) * 64 + half * 32 + quad * 8]);
#pragma unroll
      for (int j = 0; j < 4; ++j)
        bf[j] = ld8(&Bs[(wn * 64 + j * 16 + col) * 64 + half * 32 + quad * 8]);
#pragma unroll
      for (int i = 0; i < 4; ++i)
#pragma unroll
        for (int j = 0; j < 4; ++j)
          acc[i][j] = __builtin_amdgcn_mfma_f32_16x16x32_bf16(af[i], bf[j],
                                                              acc[i][j], 0, 0, 0);
    }
    __syncthreads();
  }

#pragma unroll
  for (int i = 0; i < 4; ++i)
#pragma unroll
    for (int j = 0; j < 4; ++j) {
      const int n = n0 + wn * 64 + j * 16 + col;
      float bv = 0.f;
      if (F32OUT) bv = bias[n];
#pragma unroll
      for (int r = 0; r < 4; ++r) {
        const int m = m0 + wm * 64 + i * 16 + quad * 4 + r;
        if (F32OUT)
          reinterpret_cast<float*>(Cv)[(size_t)m * 1024 + n] = acc[i][j][r] + bv;
        else
          reinterpret_cast<ushort*>(Cv)[(size_t)m * 1024 + n] = f2bf(acc[i][j][r]);
      }
    }
}

// --------------------------------------------------------------------------
// Flash attention, 128-row q-tiles. Q,K,V,O bf16 [8192][1024], O may alias Q
// (block-disjoint regions; Q read to LDS/regs before O write).
// grid 1024: pair=bid&127 -> (b=pair>>4, h=pair&15), qt=bid>>7 (XCD swizzle:
// same (b,h) => same bid%8 => same XCD L2 for K/V reuse).
// block 256 (4 waves); wave w owns rows w*32..w*32+31 (2 groups of 16).
// LDS: QP union (Qs at init, Ps in loop) + Ks + Vt = 36 KB.
// Q staging coverage: 2 thr/row -> 32 ushorts/thread (4x uint4).
// UNCHANGED from R7 (control this round).
// --------------------------------------------------------------------------
__global__ __launch_bounds__(256) void flash_attn(const ushort* __restrict__ Q,
                                                  const ushort* __restrict__ K,
                                                  const ushort* __restrict__ V,
                                                  ushort* __restrict__ O) {
  __shared__ __align__(16) ushort QP[128 * 72];
  __shared__ __align__(16) ushort Ks[64 * 72];
  __shared__ __align__(16) ushort Vt[64 * 72];
  const int pair = blockIdx.x & 127;
  const int b = pair >> 4;
  const int h = pair & 15;
  const int qt = blockIdx.x >> 7;
  const int t = threadIdx.x;
  const int lane = t & 63;
  const int w = t >> 6;
  const int col = lane & 15;
  const int quad = lane >> 4;

  const size_t base = (size_t)b * 1024 * 1024 + h * 64;
  const int qrow0 = qt * 128;

  // stage Q (128 rows x 64 cols): 32 ushorts per thread
  {
    const int row = t >> 1;
    const int c0 = (t & 1) * 32;
    const ushort* src = Q + base + (size_t)(qrow0 + row) * 1024 + c0;
    uint4 v0 = reinterpret_cast<const uint4*>(src)[0];
    uint4 v1 = reinterpret_cast<const uint4*>(src)[1];
    uint4 v2 = reinterpret_cast<const uint4*>(src)[2];
    uint4 v3 = reinterpret_cast<const uint4*>(src)[3];
    reinterpret_cast<uint4*>(&QP[row * 72 + c0])[0] = v0;
    reinterpret_cast<uint4*>(&QP[row * 72 + c0])[1] = v1;
    reinterpret_cast<uint4*>(&QP[row * 72 + c0])[2] = v2;
    reinterpret_cast<uint4*>(&QP[row * 72 + c0])[3] = v3;
  }
  __syncthreads();
  bf16x8 qa[2][2];
#pragma unroll
  for (int g = 0; g < 2; ++g)
#pragma unroll
    for (int half = 0; half < 2; ++half)
      qa[g][half] =
          ld8(&QP[(w * 32 + g * 16 + col) * 72 + half * 32 + quad * 8]);
  // qa reads complete before the first kt-staging barrier below, so reusing
  // QP as the P buffer afterwards is race-free (P writes happen only after
  // every wave has passed that barrier, hence after every qa read).

  f32x4 o_[2][4];
#pragma unroll
  for (int g = 0; g < 2; ++g)
#pragma unroll
    for (int c = 0; c < 4; ++c) o_[g][c] = (f32x4){0.f, 0.f, 0.f, 0.f};
  float m_r[2][4], l_r[2][4];
#pragma unroll
  for (int g = 0; g < 2; ++g)
#pragma unroll
    for (int r = 0; r < 4; ++r) { m_r[g][r] = -1e30f; l_r[g][r] = 0.f; }
  const float scale = 0.03125f;  // 1/sqrt(1024)

  for (int kt = 0; kt < 16; ++kt) {
    // stage K (coalesced rows; 4 thr/row x 16) and V transposed
    {
      const int srow = t >> 2;
      const int sch = (t & 3) * 16;
      const ushort* ksrc = K + base + (size_t)(kt * 64 + srow) * 1024 + sch;
      uint4 kv0 = reinterpret_cast<const uint4*>(ksrc)[0];
      uint4 kv1 = reinterpret_cast<const uint4*>(ksrc)[1];
      const int vs = t & 63;
      const int ve = (t >> 6) * 16;
      const ushort* vsrc = V + base + (size_t)(kt * 64 + vs) * 1024 + ve;
      union { uint4 u[2]; ushort s[16]; } vv;
      vv.u[0] = reinterpret_cast<const uint4*>(vsrc)[0];
      vv.u[1] = reinterpret_cast<const uint4*>(vsrc)[1];
      reinterpret_cast<uint4*>(&Ks[srow * 72 + sch])[0] = kv0;
      reinterpret_cast<uint4*>(&Ks[srow * 72 + sch])[1] = kv1;
#pragma unroll
      for (int j = 0; j < 16; ++j) Vt[(ve + j) * 72 + vs] = vv.s[j];
    }
    __syncthreads();

    // S = scale * Q K^T : both row-groups share the K fragments
    f32x4 sc[2][4];
#pragma unroll
    for (int c = 0; c < 4; ++c) {
      bf16x8 kb0 = ld8(&Ks[(c * 16 + col) * 72 + quad * 8]);
      bf16x8 kb1 = ld8(&Ks[(c * 16 + col) * 72 + 32 + quad * 8]);
#pragma unroll
      for (int g = 0; g < 2; ++g) {
        f32x4 z = {0.f, 0.f, 0.f, 0.f};
        z = __builtin_amdgcn_mfma_f32_16x16x32_bf16(qa[g][0], kb0, z, 0, 0, 0);
        z = __builtin_amdgcn_mfma_f32_16x16x32_bf16(qa[g][1], kb1, z, 0, 0, 0);
        sc[g][c] = z * scale;
      }
    }

    // online softmax; P -> QP (bf16)
#pragma unroll
    for (int g = 0; g < 2; ++g)
#pragma unroll
      for (int r = 0; r < 4; ++r) {
        float mx = fmaxf(fmaxf(sc[g][0][r], sc[g][1][r]),
                         fmaxf(sc[g][2][r], sc[g][3][r]));
        mx = fmaxf(mx, __shfl_xor(mx, 1));
        mx = fmaxf(mx, __shfl_xor(mx, 2));
        mx = fmaxf(mx, __shfl_xor(mx, 4));
        mx = fmaxf(mx, __shfl_xor(mx, 8));
        const float m_new = fmaxf(m_r[g][r], mx);
        const float alpha = __expf(m_r[g][r] - m_new);
        const float p0 = __expf(sc[g][0][r] - m_new);
        const float p1 = __expf(sc[g][1][r] - m_new);
        const float p2 = __expf(sc[g][2][r] - m_new);
        const float p3 = __expf(sc[g][3][r] - m_new);
        float rs = (p0 + p1) + (p2 + p3);
        rs += __shfl_xor(rs, 1);
        rs += __shfl_xor(rs, 2);
        rs += __shfl_xor(rs, 4);
        rs += __shfl_xor(rs, 8);
        l_r[g][r] = l_r[g][r] * alpha + rs;
        m_r[g][r] = m_new;
        o_[g][0][r] *= alpha; o_[g][1][r] *= alpha;
        o_[g][2][r] *= alpha; o_[g][3][r] *= alpha;
        const int prow = (w * 32 + g * 16 + quad * 4 + r) * 72;
        QP[prow + 0 + col] = f2bf(p0);
        QP[prow + 16 + col] = f2bf(p1);
        QP[prow + 32 + col] = f2bf(p2);
        QP[prow + 48 + col] = f2bf(p3);
      }
    __syncthreads();

    // O += P V : both row-groups share the V fragments
    bf16x8 pa[2][2];
#pragma unroll
    for (int g = 0; g < 2; ++g)
#pragma unroll
      for (int half = 0; half < 2; ++half)
        pa[g][half] =
            ld8(&QP[(w * 32 + g * 16 + col) * 72 + half * 32 + quad * 8]);
#pragma unroll
    for (int c = 0; c < 4; ++c) {
      bf16x8 vb0 = ld8(&Vt[(c * 16 + col) * 72 + quad * 8]);
      bf16x8 vb1 = ld8(&Vt[(c * 16 + col) * 72 + 32 + quad * 8]);
#pragma unroll
      for (int g = 0; g < 2; ++g) {
        o_[g][c] = __builtin_amdgcn_mfma_f32_16x16x32_bf16(pa[g][0], vb0,
                                                           o_[g][c], 0, 0, 0);
        o_[g][c] = __builtin_amdgcn_mfma_f32_16x16x32_bf16(pa[g][1], vb1,
                                                           o_[g][c], 0, 0, 0);
      }
    }
    __syncthreads();
  }

#pragma unroll
  for (int g = 0; g < 2; ++g)
#pragma unroll
    for (int r = 0; r < 4; ++r) {
      const float inv = 1.f / l_r[g][r];
      const size_t row =
          base + (size_t)(qrow0 + w * 32 + g * 16 + quad * 4 + r) * 1024;
      O[row + 0 + col] = f2bf(o_[g][0][r] * inv);
      O[row + 16 + col] = f2bf(o_[g][1][r] * inv);
      O[row + 32 + col] = f2bf(o_[g][2][r] * inv);
      O[row + 48 + col] = f2bf(o_[g][3][r] * inv);
    }
}

// --------------------------------------------------------------------------
extern "C" void kernel_launch(void* const* d_in, const int* in_sizes, int n_in,
                              void* d_out, int out_size, void* d_ws, size_t ws_size,
                              hipStream_t stream) {
  const float* q = (const float*)d_in[0];
  const float* k = (const float*)d_in[1];
  const float* v = (const float*)d_in[2];
  const float* Wq = (const float*)d_in[3];
  const float* Wk = (const float*)d_in[4];
  const float* Wv = (const float*)d_in[5];
  const float* Wo = (const float*)d_in[6];
  const float* bo = (const float*)d_in[7];
  float* out = (float*)d_out;
  ushort* ws = (ushort*)d_ws;

  const size_t M8 = 8u << 20;  // 8M bf16 = 16 MB
  const size_t M1 = 1u << 20;
  ushort* Qp = ws;                 // also flash output (in-place)
  ushort* Kp = ws + M8;
  ushort* Vp = ws + 2 * M8;
  ushort* WqT = ws + 3 * M8;
  ushort* WkT = WqT + M1;
  ushort* WvT = WkT + M1;
  ushort* WoB = WvT + M1;          // total 56 MB

  // d_out (32 MB fp32) doubles as bf16 scratch for the converted activations;
  // sequentially reused per tensor, final gemm overwrites it at the end.
  ushort* X = (ushort*)d_out;

  prep_wt<<<256, 256, 0, stream>>>(Wq, WqT);
  prep_wt<<<256, 256, 0, stream>>>(Wk, WkT);
  prep_wt<<<256, 256, 0, stream>>>(Wv, WvT);
  cvt_wo<<<256, 256, 0, stream>>>(Wo, WoB);

  cvt_wo<<<2048, 256, 0, stream>>>(q, X);
  gemm_bb<false><<<dim3(8, 64), 256, 0, stream>>>(X, WqT, nullptr, Qp);
  cvt_wo<<<2048, 256, 0, stream>>>(k, X);
  gemm_bb<false><<<dim3(8, 64), 256, 0, stream>>>(X, WkT, nullptr, Kp);
  cvt_wo<<<2048, 256, 0, stream>>>(v, X);
  gemm_bb<false><<<dim3(8, 64), 256, 0, stream>>>(X, WvT, nullptr, Vp);

  flash_attn<<<1024, 256, 0, stream>>>(Qp, Kp, Vp, Qp);

  gemm_bb<true><<<dim3(8, 64), 256, 0, stream>>>(Qp, WoB, bo, out);
}

// Round 2
// 355.802 us; speedup vs baseline: 1.3110x; 1.1615x over previous
//
#include <hip/hip_runtime.h>
#include <stdint.h>

// ---------------------------------------------------------------------------
// MultiHeadAttention: B=8 S=1024 QKV=1024 H=16 E=64 OUT=1024.
// fp32 in / fp32 out, bf16 MFMA internals, fp32 accum.
// R9: flash softmax overhaul (swapped QK^T) + merged GEMM launches.
//  - flash: QK^T computed as mfma(K_frag, Q_frag) -> D[k-row][q-col]; the
//    fragments are byte-identical to R8 (same LDS reads), only operand order
//    changes. Each lane then holds 16 P-values of ONE q-row in-lane:
//    row-reduce = in-lane + 2 shfl steps (xor16/32), vs 4-step butterfly x8.
//    P-writes: 8x 8B packed (4 consecutive k per lane), vs 32x ds_write_b16.
//    Mid-iteration barrier removed (P rows are own-wave only): 2 barriers/kt.
//    attn scale folded into Q-projection epilogue (2^-5 = exact bf16 shift).
//  - GEMM: Q+K projections merged into one 1024-block launch (4 blk/CU vs 2;
//    m114 wave-overlap needs >=3 resident); q/k cvt merged likewise.
// flash MFMA maps (HW-verified m89/m91):
//   A[m=lane&15][k=quad*8+j], B[k=quad*8+j][n=lane&15], D[row=quad*4+r][col]
// ws: [Qp 16][Kp 16][Vp 16][WqT 2|WkT 2|WvT 2|WoB 2] = 56 MB.
// d_out doubles as bf16 scratch (q~ at 0, k~ at 16MB; v~ reuses slot 0).
// ---------------------------------------------------------------------------

typedef __bf16 bf16x8 __attribute__((ext_vector_type(8)));
typedef float f32x4 __attribute__((ext_vector_type(4)));

typedef __attribute__((address_space(3))) uint32_t lds_u32;
typedef const __attribute__((address_space(1))) uint32_t glb_u32;

__device__ __forceinline__ ushort f2bf(float f) {
  uint32_t x = __float_as_uint(f);
  x += 0x7fff + ((x >> 16) & 1);  // RNE
  return (ushort)(x >> 16);
}
__device__ __forceinline__ bf16x8 ld8(const ushort* p) {
  union { uint4 u; bf16x8 b; } c;
  c.u = *reinterpret_cast<const uint4*>(p);
  return c.b;
}
__device__ __forceinline__ void cvt16(const float* __restrict__ src,
                                      ushort* __restrict__ dst) {
  union { uint4 u[2]; ushort s[16]; } o;
#pragma unroll
  for (int i = 0; i < 4; ++i) {
    const float4 f = reinterpret_cast<const float4*>(src)[i];
    o.s[4 * i + 0] = f2bf(f.x);
    o.s[4 * i + 1] = f2bf(f.y);
    o.s[4 * i + 2] = f2bf(f.z);
    o.s[4 * i + 3] = f2bf(f.w);
  }
  reinterpret_cast<uint4*>(dst)[0] = o.u[0];
  reinterpret_cast<uint4*>(dst)[1] = o.u[1];
}

// global->LDS DMA, 16B/lane. LDS dest wave-uniform base + lane*16 (m104/m108).
__device__ __forceinline__ void gld16(const ushort* g, ushort* l) {
  __builtin_amdgcn_global_load_lds((glb_u32*)g, (lds_u32*)l, 16, 0, 0);
}

// --------------------------------------------------------------------------
// W[16][1024][64] fp32 -> WT[1024][1024] bf16 (WT[n=h*64+e][k]). grid 256.
// --------------------------------------------------------------------------
__global__ __launch_bounds__(256) void prep_wt(const float* __restrict__ W,
                                               ushort* __restrict__ WT) {
  __shared__ __align__(16) ushort tile[64 * 72];
  const int h = blockIdx.x >> 4;
  const int kt = blockIdx.x & 15;
  const int t = threadIdx.x;
  const int row = t >> 2;
  const int ch = (t & 3) * 16;
  cvt16(W + ((size_t)h * 1024 + kt * 64 + row) * 64 + ch, &tile[row * 72 + ch]);
  __syncthreads();
  const int e = t >> 2;
  const int kc = (t & 3) * 16;
  ushort vals[16];
#pragma unroll
  for (int j = 0; j < 16; ++j) vals[j] = tile[(kc + j) * 72 + e];
  ushort* dst = WT + (size_t)(h * 64 + e) * 1024 + kt * 64 + kc;
  reinterpret_cast<uint4*>(dst)[0] = *reinterpret_cast<uint4*>(&vals[0]);
  reinterpret_cast<uint4*>(dst)[1] = *reinterpret_cast<uint4*>(&vals[8]);
}

// fp32 -> bf16 elementwise, 16 elems/thread. grid = elems/4096.
__global__ __launch_bounds__(256) void cvt_wo(const float* __restrict__ src,
                                              ushort* __restrict__ dst) {
  const int i = (blockIdx.x * 256 + threadIdx.x) * 16;
  cvt16(src + i, dst + i);
}

// two tensors in one launch (8M elems each). grid 4096.
__global__ __launch_bounds__(256) void cvt2(const float* __restrict__ s0,
                                            ushort* __restrict__ d0,
                                            const float* __restrict__ s1,
                                            ushort* __restrict__ d1) {
  const int b = blockIdx.x;
  const float* s = (b < 2048) ? s0 : s1;
  ushort* d = (b < 2048) ? d0 : d1;
  const int i = ((b & 2047) * 256 + threadIdx.x) * 16;
  cvt16(s + i, d + i);
}

// --------------------------------------------------------------------------
// GEMM core: C[8192][1024] = A bf16 @ Bt bf16 ^T (*oscale, + bias).
// m97 structure: 128x128 tile, BK=64, 4 waves 2x2, linear LDS, gld16 staging.
// --------------------------------------------------------------------------
template <bool F32OUT>
__device__ __forceinline__ void gemm_core(const ushort* __restrict__ A,
                                          const ushort* __restrict__ Bt,
                                          const float* __restrict__ bias,
                                          void* __restrict__ Cv, float oscale,
                                          int bx, int by) {
  __shared__ __align__(16) ushort As[128 * 64];
  __shared__ __align__(16) ushort Bs[128 * 64];
  const int n0 = bx * 128;
  const int m0 = by * 128;
  const int t = threadIdx.x;
  const int lane = t & 63;
  const int w = t >> 6;
  const int wm = w >> 1, wn = w & 1;
  const int col = lane & 15;
  const int quad = lane >> 4;
  const int gr = lane >> 3;        // 0..7
  const int gc = (lane & 7) * 8;   // ushort col 0..56

  f32x4 acc[4][4];
#pragma unroll
  for (int i = 0; i < 4; ++i)
#pragma unroll
    for (int j = 0; j < 4; ++j) acc[i][j] = (f32x4){0.f, 0.f, 0.f, 0.f};

  const ushort* a_src = A + (size_t)(m0 + w * 8 + gr) * 1024 + gc;
  const ushort* b_src = Bt + (size_t)(n0 + w * 8 + gr) * 1024 + gc;
  ushort* as_base = &As[(w * 8) * 64];
  ushort* bs_base = &Bs[(w * 8) * 64];

  for (int k0 = 0; k0 < 1024; k0 += 64) {
#pragma unroll
    for (int c = 0; c < 4; ++c) {
      gld16(a_src + (size_t)c * 32 * 1024 + k0, as_base + c * 32 * 64);
      gld16(b_src + (size_t)c * 32 * 1024 + k0, bs_base + c * 32 * 64);
    }
    __syncthreads();

#pragma unroll
    for (int half = 0; half < 2; ++half) {
      bf16x8 af[4], bfr[4];
#pragma unroll
      for (int i = 0; i < 4; ++i)
        af[i] = ld8(&As[(wm * 64 + i * 16 + col) * 64 + half * 32 + quad * 8]);
#pragma unroll
      for (int j = 0; j < 4; ++j)
        bfr[j] = ld8(&Bs[(wn * 64 + j * 16 + col) * 64 + half * 32 + quad * 8]);
#pragma unroll
      for (int i = 0; i < 4; ++i)
#pragma unroll
        for (int j = 0; j < 4; ++j)
          acc[i][j] = __builtin_amdgcn_mfma_f32_16x16x32_bf16(af[i], bfr[j],
                                                              acc[i][j], 0, 0, 0);
    }
    __syncthreads();
  }

#pragma unroll
  for (int i = 0; i < 4; ++i)
#pragma unroll
    for (int j = 0; j < 4; ++j) {
      const int n = n0 + wn * 64 + j * 16 + col;
      float bv = 0.f;
      if (F32OUT) bv = bias[n];
#pragma unroll
      for (int r = 0; r < 4; ++r) {
        const int m = m0 + wm * 64 + i * 16 + quad * 4 + r;
        if (F32OUT)
          reinterpret_cast<float*>(Cv)[(size_t)m * 1024 + n] = acc[i][j][r] + bv;
        else
          reinterpret_cast<ushort*>(Cv)[(size_t)m * 1024 + n] =
              f2bf(acc[i][j][r] * oscale);
      }
    }
}

template <bool F32OUT>
__global__ __launch_bounds__(256) void gemm_bb(const ushort* __restrict__ A,
                                               const ushort* __restrict__ Bt,
                                               const float* __restrict__ bias,
                                               void* __restrict__ Cv,
                                               float oscale) {
  gemm_core<F32OUT>(A, Bt, bias, Cv, oscale, blockIdx.x, blockIdx.y);
}

// Q and K projections in one launch: grid dim3(8, 64, 2) -> 1024 blocks.
__global__ __launch_bounds__(256) void gemm_proj2(
    const ushort* __restrict__ A0, const ushort* __restrict__ B0,
    ushort* __restrict__ C0, float s0, const ushort* __restrict__ A1,
    const ushort* __restrict__ B1, ushort* __restrict__ C1, float s1) {
  if (blockIdx.z == 0)
    gemm_core<false>(A0, B0, nullptr, C0, s0, blockIdx.x, blockIdx.y);
  else
    gemm_core<false>(A1, B1, nullptr, C1, s1, blockIdx.x, blockIdx.y);
}

// --------------------------------------------------------------------------
// Flash attention, 128-row q-tiles. Q,K,V,O bf16 [8192][1024], O aliases Q.
// Q is PRE-SCALED by 1/sqrt(1024) (folded into the Q projection).
// grid 1024: pair=bid&127 -> (b,h), qt=bid>>7 (XCD-friendly: same (b,h) =>
// same bid%8). block 256 (4 waves); wave w owns q-rows w*32..w*32+31.
// Swapped QK^T: sc[g][c] = mfma(K_frag, Q_frag) -> D[m=k-row][n=q-row].
// Lane owns q-row (lane&15) per g: in-lane 16-value reduce + shfl_xor 16/32.
// P pack: 4 consecutive k (c*16+quad*4..+3) -> one 8B write per (g,c).
// Barriers: 2/kt (mid barrier removed; P rows are own-wave write+read).
// --------------------------------------------------------------------------
__global__ __launch_bounds__(256) void flash_attn(const ushort* __restrict__ Q,
                                                  const ushort* __restrict__ K,
                                                  const ushort* __restrict__ V,
                                                  ushort* __restrict__ O) {
  __shared__ __align__(16) ushort QP[128 * 72];
  __shared__ __align__(16) ushort Ks[64 * 72];
  __shared__ __align__(16) ushort Vt[64 * 72];
  const int pair = blockIdx.x & 127;
  const int b = pair >> 4;
  const int h = pair & 15;
  const int qt = blockIdx.x >> 7;
  const int t = threadIdx.x;
  const int lane = t & 63;
  const int w = t >> 6;
  const int col = lane & 15;
  const int quad = lane >> 4;

  const size_t base = (size_t)b * 1024 * 1024 + h * 64;
  const int qrow0 = qt * 128;

  // stage Q (128 x 64): 32 ushorts per thread
  {
    const int row = t >> 1;
    const int c0 = (t & 1) * 32;
    const ushort* src = Q + base + (size_t)(qrow0 + row) * 1024 + c0;
    uint4 v0 = reinterpret_cast<const uint4*>(src)[0];
    uint4 v1 = reinterpret_cast<const uint4*>(src)[1];
    uint4 v2 = reinterpret_cast<const uint4*>(src)[2];
    uint4 v3 = reinterpret_cast<const uint4*>(src)[3];
    reinterpret_cast<uint4*>(&QP[row * 72 + c0])[0] = v0;
    reinterpret_cast<uint4*>(&QP[row * 72 + c0])[1] = v1;
    reinterpret_cast<uint4*>(&QP[row * 72 + c0])[2] = v2;
    reinterpret_cast<uint4*>(&QP[row * 72 + c0])[3] = v3;
  }
  __syncthreads();
  bf16x8 qa[2][2];
#pragma unroll
  for (int g = 0; g < 2; ++g)
#pragma unroll
    for (int half = 0; half < 2; ++half)
      qa[g][half] =
          ld8(&QP[(w * 32 + g * 16 + col) * 72 + half * 32 + quad * 8]);
  // qa reads complete before the first kt staging barrier -> reusing QP as
  // the P buffer afterwards is race-free.

  f32x4 o_[2][4];
#pragma unroll
  for (int g = 0; g < 2; ++g)
#pragma unroll
    for (int c = 0; c < 4; ++c) o_[g][c] = (f32x4){0.f, 0.f, 0.f, 0.f};
  // per-lane softmax state for q-row = (w*32 + g*16 + (lane&15))
  float m_s[2] = {-1e30f, -1e30f};
  float l_s[2] = {0.f, 0.f};

  for (int kt = 0; kt < 16; ++kt) {
    // stage K (coalesced rows) and V transposed
    {
      const int srow = t >> 2;
      const int sch = (t & 3) * 16;
      const ushort* ksrc = K + base + (size_t)(kt * 64 + srow) * 1024 + sch;
      uint4 kv0 = reinterpret_cast<const uint4*>(ksrc)[0];
      uint4 kv1 = reinterpret_cast<const uint4*>(ksrc)[1];
      const int vs = t & 63;
      const int ve = (t >> 6) * 16;
      const ushort* vsrc = V + base + (size_t)(kt * 64 + vs) * 1024 + ve;
      union { uint4 u[2]; ushort s[16]; } vv;
      vv.u[0] = reinterpret_cast<const uint4*>(vsrc)[0];
      vv.u[1] = reinterpret_cast<const uint4*>(vsrc)[1];
      reinterpret_cast<uint4*>(&Ks[srow * 72 + sch])[0] = kv0;
      reinterpret_cast<uint4*>(&Ks[srow * 72 + sch])[1] = kv1;
#pragma unroll
      for (int j = 0; j < 16; ++j) Vt[(ve + j) * 72 + vs] = vv.s[j];
    }
    __syncthreads();

    // S^T = K Q^T (swapped operands; fragments identical to the unswapped
    // form). sc[g][c][r] = S[q = lane&15 (+g*16+w*32)][k = c*16+quad*4+r].
    f32x4 sc[2][4];
#pragma unroll
    for (int c = 0; c < 4; ++c) {
      bf16x8 kb0 = ld8(&Ks[(c * 16 + col) * 72 + quad * 8]);
      bf16x8 kb1 = ld8(&Ks[(c * 16 + col) * 72 + 32 + quad * 8]);
#pragma unroll
      for (int g = 0; g < 2; ++g) {
        f32x4 z = {0.f, 0.f, 0.f, 0.f};
        z = __builtin_amdgcn_mfma_f32_16x16x32_bf16(kb0, qa[g][0], z, 0, 0, 0);
        z = __builtin_amdgcn_mfma_f32_16x16x32_bf16(kb1, qa[g][1], z, 0, 0, 0);
        sc[g][c] = z;
      }
    }

    // online softmax, row-local: in-lane reduce + 2 butterfly steps
    float al[2];
#pragma unroll
    for (int g = 0; g < 2; ++g) {
      float mx = sc[g][0][0];
#pragma unroll
      for (int c = 0; c < 4; ++c)
#pragma unroll
        for (int r = 0; r < 4; ++r) mx = fmaxf(mx, sc[g][c][r]);
      mx = fmaxf(mx, __shfl_xor(mx, 16));
      mx = fmaxf(mx, __shfl_xor(mx, 32));
      const float m_new = fmaxf(m_s[g], mx);
      al[g] = __expf(m_s[g] - m_new);
      m_s[g] = m_new;
      float rs = 0.f;
      const int prow = (w * 32 + g * 16 + col) * 72;
#pragma unroll
      for (int c = 0; c < 4; ++c) {
        const float p0 = __expf(sc[g][c][0] - m_new);
        const float p1 = __expf(sc[g][c][1] - m_new);
        const float p2 = __expf(sc[g][c][2] - m_new);
        const float p3 = __expf(sc[g][c][3] - m_new);
        rs += (p0 + p1) + (p2 + p3);
        union { uint2 u; ushort s[4]; } pk;
        pk.s[0] = f2bf(p0);
        pk.s[1] = f2bf(p1);
        pk.s[2] = f2bf(p2);
        pk.s[3] = f2bf(p3);
        *reinterpret_cast<uint2*>(&QP[prow + c * 16 + quad * 4]) = pk.u;
      }
      rs += __shfl_xor(rs, 16);
      rs += __shfl_xor(rs, 32);
      l_s[g] = l_s[g] * al[g] + rs;
    }

    // rescale O with per-row alpha (row q = quad*4+r lives at lane&15 == q)
#pragma unroll
    for (int g = 0; g < 2; ++g)
#pragma unroll
      for (int r = 0; r < 4; ++r) {
        const float a = __shfl(al[g], (lane & 48) | (quad * 4 + r));
        o_[g][0][r] *= a;
        o_[g][1][r] *= a;
        o_[g][2][r] *= a;
        o_[g][3][r] *= a;
      }

    // O += P V (P rows written and read by the same wave; in-wave DS order
    // suffices -> no barrier needed here)
    bf16x8 pa[2][2];
#pragma unroll
    for (int g = 0; g < 2; ++g)
#pragma unroll
      for (int half = 0; half < 2; ++half)
        pa[g][half] =
            ld8(&QP[(w * 32 + g * 16 + col) * 72 + half * 32 + quad * 8]);
#pragma unroll
    for (int c = 0; c < 4; ++c) {
      bf16x8 vb0 = ld8(&Vt[(c * 16 + col) * 72 + quad * 8]);
      bf16x8 vb1 = ld8(&Vt[(c * 16 + col) * 72 + 32 + quad * 8]);
#pragma unroll
      for (int g = 0; g < 2; ++g) {
        o_[g][c] = __builtin_amdgcn_mfma_f32_16x16x32_bf16(pa[g][0], vb0,
                                                           o_[g][c], 0, 0, 0);
        o_[g][c] = __builtin_amdgcn_mfma_f32_16x16x32_bf16(pa[g][1], vb1,
                                                           o_[g][c], 0, 0, 0);
      }
    }
    __syncthreads();
  }

#pragma unroll
  for (int g = 0; g < 2; ++g)
#pragma unroll
    for (int r = 0; r < 4; ++r) {
      const float lr = __shfl(l_s[g], (lane & 48) | (quad * 4 + r));
      const float inv = 1.f / lr;
      const size_t row =
          base + (size_t)(qrow0 + w * 32 + g * 16 + quad * 4 + r) * 1024;
      O[row + 0 + col] = f2bf(o_[g][0][r] * inv);
      O[row + 16 + col] = f2bf(o_[g][1][r] * inv);
      O[row + 32 + col] = f2bf(o_[g][2][r] * inv);
      O[row + 48 + col] = f2bf(o_[g][3][r] * inv);
    }
}

// --------------------------------------------------------------------------
extern "C" void kernel_launch(void* const* d_in, const int* in_sizes, int n_in,
                              void* d_out, int out_size, void* d_ws, size_t ws_size,
                              hipStream_t stream) {
  const float* q = (const float*)d_in[0];
  const float* k = (const float*)d_in[1];
  const float* v = (const float*)d_in[2];
  const float* Wq = (const float*)d_in[3];
  const float* Wk = (const float*)d_in[4];
  const float* Wv = (const float*)d_in[5];
  const float* Wo = (const float*)d_in[6];
  const float* bo = (const float*)d_in[7];
  float* out = (float*)d_out;
  ushort* ws = (ushort*)d_ws;

  const size_t M8 = 8u << 20;  // 8M bf16 = 16 MB
  const size_t M1 = 1u << 20;
  ushort* Qp = ws;                 // also flash output (in-place)
  ushort* Kp = ws + M8;
  ushort* Vp = ws + 2 * M8;
  ushort* WqT = ws + 3 * M8;
  ushort* WkT = WqT + M1;
  ushort* WvT = WkT + M1;
  ushort* WoB = WvT + M1;          // total 56 MB

  // d_out (32 MB fp32) as bf16 scratch: q~ at 0, k~ at +16MB; v~ reuses 0.
  ushort* X0 = (ushort*)d_out;
  ushort* X1 = X0 + M8;

  prep_wt<<<256, 256, 0, stream>>>(Wq, WqT);
  prep_wt<<<256, 256, 0, stream>>>(Wk, WkT);
  prep_wt<<<256, 256, 0, stream>>>(Wv, WvT);
  cvt_wo<<<256, 256, 0, stream>>>(Wo, WoB);

  cvt2<<<4096, 256, 0, stream>>>(q, X0, k, X1);
  // attn scale folded into Q projection (exact: 2^-5 exponent shift in bf16)
  gemm_proj2<<<dim3(8, 64, 2), 256, 0, stream>>>(X0, WqT, Qp, 0.03125f,
                                                 X1, WkT, Kp, 1.0f);
  cvt_wo<<<2048, 256, 0, stream>>>(v, X0);
  gemm_bb<false><<<dim3(8, 64), 256, 0, stream>>>(X0, WvT, nullptr, Vp, 1.0f);

  flash_attn<<<1024, 256, 0, stream>>>(Qp, Kp, Vp, Qp);

  gemm_bb<true><<<dim3(8, 64), 256, 0, stream>>>(Qp, WoB, bo, out, 1.0f);
}